// Round 4
// baseline (31128.226 us; speedup 1.0000x reference)
//
#include <hip/hip_runtime.h>

#define TRAJ 4
#define BATCH 256
#define DIM 256
#define HID 1024
#define NT 50
#define NSAMP (TRAJ*BATCH)   // 1024
#define MB 16                // samples per block
#define NBLK (NSAMP/MB)      // 64
#define NTHR 512             // 8 waves

// swizzled-weight offsets in d_ws (ushort elements)
#define W1OFF 0
#define W2OFF (DIM*HID)              // 262144
#define W3OFF (W2OFF + HID*HID)      // 1310720

typedef __bf16 bf16x8 __attribute__((ext_vector_type(8)));
typedef float  f32x4  __attribute__((ext_vector_type(4)));
typedef unsigned int uint4v __attribute__((ext_vector_type(4)));

__device__ __forceinline__ unsigned short f2bf(float x) {
    unsigned int b = __float_as_uint(x);
    b += 0x7fffu + ((b >> 16) & 1u);   // round-to-nearest-even
    return (unsigned short)(b >> 16);
}

__device__ __forceinline__ float ftanh(float x) {
    float e = __expf(2.0f * x);
    return 1.0f - 2.0f * __builtin_amdgcn_rcpf(e + 1.0f);
}

__device__ __forceinline__ f32x4 mfma16(uint4v a, uint4v b, f32x4 c) {
    return __builtin_amdgcn_mfma_f32_16x16x32_bf16(
        __builtin_bit_cast(bf16x8, a), __builtin_bit_cast(bf16x8, b), c, 0, 0, 0);
}

// ---------------------------------------------------------------------------
// Prep: swizzle f32 weights into bf16 MFMA B-fragment order in d_ws.
// Fragment (ct, ks): 64 lanes x 8 bf16; element j of lane l =
//   W[ks*32 + (l>>4)*8 + j][ct*16 + (l&15)]
// ---------------------------------------------------------------------------
__global__ void prep_kernel(const float* __restrict__ W1,
                            const float* __restrict__ W2,
                            const float* __restrict__ W3,
                            unsigned short* __restrict__ ws) {
    int bid = blockIdx.x;
    int lane = threadIdx.x;
    const float* W;
    int ncol;
    unsigned short* dst;
    int ct, ks;
    if (bid < 512) {                       // W1: [256][1024], 64 ct x 8 ks
        W = W1; ncol = 1024; ct = bid >> 3; ks = bid & 7;
        dst = ws + W1OFF + ((size_t)bid * 64 + lane) * 8;
    } else if (bid < 2560) {               // W2: [1024][1024], 64 ct x 32 ks
        int b = bid - 512;
        W = W2; ncol = 1024; ct = b >> 5; ks = b & 31;
        dst = ws + W2OFF + ((size_t)b * 64 + lane) * 8;
    } else {                               // W3: [1024][256], 16 ct x 32 ks
        int b = bid - 2560;
        W = W3; ncol = 256; ct = b >> 5; ks = b & 31;
        dst = ws + W3OFF + ((size_t)b * 64 + lane) * 8;
    }
    int col = ct * 16 + (lane & 15);
    int k0  = ks * 32 + (lane >> 4) * 8;
    unsigned short v[8];
#pragma unroll
    for (int j = 0; j < 8; ++j)
        v[j] = f2bf(W[(k0 + j) * ncol + col]);
    *(uint4v*)dst = *(const uint4v*)v;
}

// raw barrier: drain LDS ops only; global prefetch loads stay in flight
#define BAR() do { \
    asm volatile("s_waitcnt lgkmcnt(0)" ::: "memory"); \
    __builtin_amdgcn_s_barrier(); \
    asm volatile("" ::: "memory"); \
} while (0)

#define LDW(p) (*(const uint4v*)(p))

// issue 8 weight fragments of a group into buffer slot b
#define ISS_L1(g, b) { _Pragma("unroll") \
    for (int _c = 0; _c < 8; ++_c) B[b][_c] = LDW(w1b + (size_t)(_c * 8 + (g)) * 512); }
#define ISS_L2(g, b) { _Pragma("unroll") \
    for (int _c = 0; _c < 8; ++_c) B[b][_c] = LDW(w2b + (size_t)(_c * 32 + (g)) * 512); }
#define ISS_L3(g, b) { _Pragma("unroll") \
    for (int _i = 0; _i < 8; ++_i) B[b][_i] = LDW(w3b + \
        (size_t)((_i >> 2) * 32 + ((g) >> 1) * 8 + ((g) & 1) * 4 + (_i & 3)) * 512); }

// ---------------------------------------------------------------------------
// Main: persistent per-sample-block RK4 integrator. 64 blocks x 16 samples.
// Depth-2 register prefetch pipeline over 48 weight-fragment groups/stage.
// ---------------------------------------------------------------------------
__global__ __launch_bounds__(NTHR, 2) void ode_main(
        const float* __restrict__ y0g, const float* __restrict__ ts,
        const float* __restrict__ b1g, const float* __restrict__ b2g,
        const float* __restrict__ b3g,
        const unsigned short* __restrict__ wsw, float* __restrict__ out) {

    __shared__ __align__(16) unsigned short ys[MB][DIM + 8];   // stage input, bf16
    __shared__ __align__(16) unsigned short h1[MB][HID + 8];
    __shared__ __align__(16) unsigned short h2[MB][HID + 8];

    const int tid  = threadIdx.x;
    const int wave = tid >> 6;
    const int lane = tid & 63;
    const int lr   = lane & 15;     // tile col (and A-row)
    const int lg   = lane >> 4;     // lane group: C rows lg*4..lg*4+3, A k-chunk
    const int s0   = blockIdx.x * MB;
    const int hc0  = wave * 128;    // this wave's H-column base (layers 1,2)
    const int dc0  = wave * 32;     // this wave's D-column base (layer 3 / y)

    // lane-resident weight base pointers
    const unsigned short* w1b = wsw + W1OFF + (size_t)wave * 64 * 512 + lane * 8;
    const unsigned short* w2b = wsw + W2OFF + (size_t)wave * 256 * 512 + lane * 8;
    const unsigned short* w3b = wsw + W3OFF + (size_t)wave * 64 * 512 + lane * 8;

    // biases, preloaded once
    float bias1[8], bias2[8], bias3[2];
#pragma unroll
    for (int t = 0; t < 8; ++t) {
        bias1[t] = b1g[hc0 + t * 16 + lr];
        bias2[t] = b2g[hc0 + t * 16 + lr];
    }
    bias3[0] = b3g[dc0 + lr];
    bias3[1] = b3g[dc0 + 16 + lr];

    // init: y registers (C-frag positions), seed ys LDS, write out[t=0]
    float yreg[2][4];
#pragma unroll
    for (int t = 0; t < 2; ++t)
#pragma unroll
        for (int j = 0; j < 4; ++j) {
            int row = lg * 4 + j, col = dc0 + t * 16 + lr;
            float v = y0g[(s0 + row) * DIM + col];
            yreg[t][j] = v;
            ys[row][col] = f2bf(v);
            __builtin_nontemporal_store(v, &out[((s0 + row) * NT + 0) * DIM + col]);
        }
    __syncthreads();

    uint4v B[3][8];                 // rotating prefetch buffers (static-indexed)
    float acc[2][4];
    const f32x4 z4 = {0.f, 0.f, 0.f, 0.f};

    // prologue: prefetch first two groups of layer 1
    ISS_L1(0, 0);
    ISS_L1(1, 1);

#pragma unroll 1
    for (int step = 1; step < NT; ++step) {
        float dt = ts[step] - ts[step - 1];
#pragma unroll 1
        for (int stage = 0; stage < 4; ++stage) {
            // ======== layer 1: h1 = tanh(ys @ W1 + b1) — groups p=0..7 ========
            {
                f32x4 c1[8];
#pragma unroll
                for (int c = 0; c < 8; ++c) c1[c] = z4;
#pragma unroll
                for (int g = 0; g < 8; ++g) {
                    if (g < 6) { ISS_L1(g + 2, (g + 2) % 3); }
                    else       { ISS_L2(g - 6, (g + 2) % 3); }
                    uint4v a = *(const uint4v*)&ys[lr][g * 32 + lg * 8];
#pragma unroll
                    for (int c = 0; c < 8; ++c)
                        c1[c] = mfma16(a, B[g % 3][c], c1[c]);
                }
#pragma unroll
                for (int c = 0; c < 8; ++c)
#pragma unroll
                    for (int j = 0; j < 4; ++j)
                        h1[lg * 4 + j][hc0 + c * 16 + lr] = f2bf(ftanh(c1[c][j] + bias1[c]));
            }
            BAR();

            // ======== layer 2: h2 = tanh(h1 @ W2 + b2) — groups p=8..39 =======
            {
                f32x4 c2[8];
#pragma unroll
                for (int c = 0; c < 8; ++c) c2[c] = z4;
#pragma unroll
                for (int g = 0; g < 32; ++g) {
                    if (g < 30) { ISS_L2(g + 2, (g + 10) % 3); }
                    else        { ISS_L3(g - 30, (g + 10) % 3); }
                    uint4v a = *(const uint4v*)&h1[lr][(g >> 3) * 256 + (g & 7) * 32 + lg * 8];
#pragma unroll
                    for (int c = 0; c < 8; ++c)
                        c2[c] = mfma16(a, B[(g + 8) % 3][c], c2[c]);
                }
#pragma unroll
                for (int c = 0; c < 8; ++c)
#pragma unroll
                    for (int j = 0; j < 4; ++j)
                        h2[lg * 4 + j][hc0 + c * 16 + lr] = f2bf(ftanh(c2[c][j] + bias2[c]));
            }
            BAR();

            // ======== layer 3: k = h2 @ W3 + b3; RK4 update — p=40..47 ========
            {
                f32x4 c3p[2][2];
                c3p[0][0] = z4; c3p[0][1] = z4; c3p[1][0] = z4; c3p[1][1] = z4;
#pragma unroll
                for (int g = 0; g < 8; ++g) {
                    if (g < 6) { ISS_L3(g + 2, (g + 42) % 3); }
                    else       { ISS_L1(g - 6, (g + 42) % 3); }   // next stage/step L1
                    uint4v a[4];
#pragma unroll
                    for (int q = 0; q < 4; ++q)
                        a[q] = *(const uint4v*)
                            &h2[lr][(g >> 1) * 256 + ((g & 1) * 4 + q) * 32 + lg * 8];
#pragma unroll
                    for (int q = 0; q < 4; ++q)
#pragma unroll
                        for (int c = 0; c < 2; ++c)
                            c3p[c][q & 1] = mfma16(a[q], B[(g + 40) % 3][c * 4 + q], c3p[c][q & 1]);
                }

                float accw = (stage == 0 || stage == 3) ? 1.0f : 2.0f;
                float cin  = (stage == 2) ? dt : 0.5f * dt;
#pragma unroll
                for (int t = 0; t < 2; ++t)
#pragma unroll
                    for (int j = 0; j < 4; ++j) {
                        float kv = c3p[t][0][j] + c3p[t][1][j] + bias3[t];
                        acc[t][j] = (stage == 0) ? kv : acc[t][j] + accw * kv;
                        float ysv;
                        if (stage < 3) {
                            ysv = yreg[t][j] + cin * kv;
                        } else {
                            yreg[t][j] += dt * (1.0f / 6.0f) * acc[t][j];
                            ysv = yreg[t][j];
                            __builtin_nontemporal_store(
                                ysv, &out[((s0 + lg * 4 + j) * NT + step) * DIM + dc0 + t * 16 + lr]);
                        }
                        ys[lg * 4 + j][dc0 + t * 16 + lr] = f2bf(ysv);
                    }
            }
            BAR();
        }
    }
}

extern "C" void kernel_launch(void* const* d_in, const int* in_sizes, int n_in,
                              void* d_out, int out_size, void* d_ws, size_t ws_size,
                              hipStream_t stream) {
    const float* y0 = (const float*)d_in[0];
    const float* ts = (const float*)d_in[1];
    const float* W1 = (const float*)d_in[2];
    const float* b1 = (const float*)d_in[3];
    const float* W2 = (const float*)d_in[4];
    const float* b2 = (const float*)d_in[5];
    const float* W3 = (const float*)d_in[6];
    const float* b3 = (const float*)d_in[7];
    unsigned short* ws = (unsigned short*)d_ws;
    float* out = (float*)d_out;

    prep_kernel<<<3072, 64, 0, stream>>>(W1, W2, W3, ws);
    ode_main<<<NBLK, NTHR, 0, stream>>>(y0, ts, b1, b2, b3, ws, out);
}

// Round 7
// 4828.909 us; speedup vs baseline: 6.4462x; 6.4462x over previous
//
#include <hip/hip_runtime.h>

#define TRAJ 4
#define BATCH 256
#define DIM 256
#define HID 1024
#define NT 50
#define NSAMP (TRAJ*BATCH)   // 1024
#define MB 16                // samples per block
#define NBLK (NSAMP/MB)      // 64
#define NTHR 512             // 8 waves

// d_ws layout (ushort elems): per wave w (0..7): 384 fragments of 512 ushorts
// (1KB) in exact stream order: [L1: 64 frags][L2: 256][L3: 64].
// Chunk c (0..191) = frags 2c, 2c+1.
#define WAVE_WS 196608       // 384 frags * 512 ushorts

typedef __bf16 bf16x8 __attribute__((ext_vector_type(8)));
typedef float  f32x4  __attribute__((ext_vector_type(4)));
typedef unsigned int uint4v __attribute__((ext_vector_type(4)));

__device__ __forceinline__ unsigned short f2bf(float x) {
    unsigned int b = __float_as_uint(x);
    b += 0x7fffu + ((b >> 16) & 1u);   // round-to-nearest-even
    return (unsigned short)(b >> 16);
}

__device__ __forceinline__ float ftanh(float x) {
    float e = __expf(2.0f * x);
    return 1.0f - 2.0f * __builtin_amdgcn_rcpf(e + 1.0f);
}

__device__ __forceinline__ f32x4 mfma16(uint4v a, uint4v b, f32x4 c) {
    return __builtin_amdgcn_mfma_f32_16x16x32_bf16(
        __builtin_bit_cast(bf16x8, a), __builtin_bit_cast(bf16x8, b), c, 0, 0, 0);
}

// async global->LDS DMA: 16B per lane, LDS dest = wave-uniform base + lane*16
__device__ __forceinline__ void gld_lds16(const unsigned short* g, unsigned short* l) {
    __builtin_amdgcn_global_load_lds(
        (const __attribute__((address_space(1))) unsigned int*)g,
        (__attribute__((address_space(3))) unsigned int*)l, 16, 0, 0);
}

// ---------------------------------------------------------------------------
// Prep: swizzle f32 weights -> bf16 fragments in per-wave stream order.
// One 64-lane block per fragment; bid = w*384 + r.
// Fragment element j of lane l = W[g*32 + (l>>4)*8 + j][colbase + (l&15)]
// ---------------------------------------------------------------------------
__global__ void prep_kernel(const float* __restrict__ W1,
                            const float* __restrict__ W2,
                            const float* __restrict__ W3,
                            unsigned short* __restrict__ ws) {
    int bid  = blockIdx.x;           // 0..3071
    int lane = threadIdx.x;
    int w = bid / 384;
    int r = bid % 384;
    const float* W;
    int ncol, colbase, g;
    if (r < 64) {                    // L1
        W = W1; ncol = 1024; g = r >> 3;
        colbase = w * 128 + (r & 7) * 16;
    } else if (r < 320) {            // L2
        int q = r - 64;
        W = W2; ncol = 1024; g = q >> 3;
        colbase = w * 128 + (q & 7) * 16;
    } else {                         // L3
        int q = r - 320;
        W = W3; ncol = 256; g = q >> 1;
        colbase = w * 32 + (q & 1) * 16;
    }
    int col = colbase + (lane & 15);
    int k0  = g * 32 + (lane >> 4) * 8;
    unsigned short v[8];
#pragma unroll
    for (int j = 0; j < 8; ++j)
        v[j] = f2bf(W[(k0 + j) * ncol + col]);
    *(uint4v*)(ws + (size_t)bid * 512 + lane * 8) = *(const uint4v*)v;
}

// barrier draining LDS ops only; global DMA stays in flight
#define BAR() do { \
    asm volatile("s_waitcnt lgkmcnt(0)" ::: "memory"); \
    __builtin_amdgcn_s_barrier(); \
    asm volatile("" ::: "memory"); \
} while (0)

// wait: all but the newest 2 VMEM ops retired => chunk c+1 landed in LDS
#define VMW2() asm volatile("s_waitcnt vmcnt(2)" ::: "memory")

// issue chunk cc (2 frags = 2KB) of this wave's stream into ring slot cc&3
#define ISSUE(cc) do { \
    const unsigned short* _s = wlane + (size_t)(cc) * 1024; \
    unsigned short* _d = ringw + ((cc) & 3) * 1024; \
    gld_lds16(_s, _d); \
    gld_lds16(_s + 512, _d + 512); \
} while (0)

#define RD(slot, f) (*(const uint4v*)(ringw + (slot) * 1024 + (f) * 512 + lane * 8))

// ---------------------------------------------------------------------------
// Main: persistent per-sample-block RK4 integrator. 64 blocks x 16 samples.
// Weights streamed via global_load_lds into per-wave 4-slot x 2KB LDS ring.
// Read-first / wait-for-next schedule, issue-ahead 2:
//   iter c: ds_read(chunk c)  [retirement confirmed at iter c-1's wait,
//                              with a full MFMA block of separation]
//           ISSUE(c+2)        [slot (c+2)&3 -> overwrite of slot c&3 happens
//                              2 iterations after its read: WAR margin 2]
//           vmcnt(2)          [the 2 newest ops = chunk c+2 -> c+1 retired]
//           MFMAs(chunk c)
// 192 chunks/stage/wave; sequence wraps across layers/stages/steps.
// ---------------------------------------------------------------------------
__global__ __launch_bounds__(NTHR, 2) void ode_main(
        const float* __restrict__ y0g, const float* __restrict__ ts,
        const float* __restrict__ b1g, const float* __restrict__ b2g,
        const float* __restrict__ b3g,
        const unsigned short* __restrict__ wsw, float* __restrict__ out) {

    __shared__ __align__(16) unsigned short ys[MB][DIM + 8];   // stage input
    __shared__ __align__(16) unsigned short h1[MB][HID + 8];
    __shared__ __align__(16) unsigned short h2[MB][HID + 8];
    __shared__ __align__(16) unsigned short ring[8][4][1024];  // 64KB DMA ring

    const int tid  = threadIdx.x;
    const int wave = tid >> 6;
    const int lane = tid & 63;
    const int lr   = lane & 15;     // tile col (and A-row)
    const int lg   = lane >> 4;     // lane group: C rows lg*4..lg*4+3, A k-chunk
    const int s0   = blockIdx.x * MB;
    const int hc0  = wave * 128;    // this wave's H-column base (layers 1,2)
    const int dc0  = wave * 32;     // this wave's D-column base (layer 3 / y)

    const unsigned short* wlane = wsw + (size_t)wave * WAVE_WS + lane * 8;
    unsigned short* ringw = &ring[wave][0][0];

    // biases
    float bias1[8], bias2[8], bias3[2];
#pragma unroll
    for (int t = 0; t < 8; ++t) {
        bias1[t] = b1g[hc0 + t * 16 + lr];
        bias2[t] = b2g[hc0 + t * 16 + lr];
    }
    bias3[0] = b3g[dc0 + lr];
    bias3[1] = b3g[dc0 + 16 + lr];

    // init: y registers, seed ys LDS, write out[t=0]
    float yreg[2][4];
#pragma unroll
    for (int t = 0; t < 2; ++t)
#pragma unroll
        for (int j = 0; j < 4; ++j) {
            int row = lg * 4 + j, col = dc0 + t * 16 + lr;
            float v = y0g[(s0 + row) * DIM + col];
            yreg[t][j] = v;
            ys[row][col] = f2bf(v);
            __builtin_nontemporal_store(v, &out[((s0 + row) * NT + 0) * DIM + col]);
        }
    __syncthreads();   // full drain (incl. vmcnt) before the pipeline starts

    float acc[2][4];
    const f32x4 z4 = {0.f, 0.f, 0.f, 0.f};

    // prologue: 2 chunks ahead; vmcnt(2) leaves chunk 1 in flight => chunk 0 landed
    ISSUE(0); ISSUE(1);
    VMW2();

#pragma unroll 1
    for (int step = 1; step < NT; ++step) {
        float dt = ts[step] - ts[step - 1];
#pragma unroll 1
        for (int stage = 0; stage < 4; ++stage) {
            // ======== layer 1: h1 = tanh(ys @ W1 + b1) — chunks 0..31 ========
            {
                f32x4 c1[8];
#pragma unroll
                for (int c = 0; c < 8; ++c) c1[c] = z4;
#pragma unroll
                for (int g = 0; g < 8; ++g) {
                    uint4v a1 = *(const uint4v*)&ys[lr][g * 32 + lg * 8];
#pragma unroll
                    for (int p = 0; p < 4; ++p) {
                        const int c = g * 4 + p;
                        uint4v b0 = RD(c & 3, 0), b1 = RD(c & 3, 1);
                        ISSUE(c + 2);
                        VMW2();
                        c1[2 * p]     = mfma16(a1, b0, c1[2 * p]);
                        c1[2 * p + 1] = mfma16(a1, b1, c1[2 * p + 1]);
                    }
                }
#pragma unroll
                for (int c = 0; c < 8; ++c)
#pragma unroll
                    for (int j = 0; j < 4; ++j)
                        h1[lg * 4 + j][hc0 + c * 16 + lr] = f2bf(ftanh(c1[c][j] + bias1[c]));
            }
            BAR();

            // ======== layer 2: h2 = tanh(h1 @ W2 + b2) — chunks 32..159 ======
            {
                f32x4 c2[8];
#pragma unroll
                for (int c = 0; c < 8; ++c) c2[c] = z4;
#pragma unroll 4
                for (int g = 0; g < 32; ++g) {
                    uint4v a = *(const uint4v*)&h1[lr][g * 32 + lg * 8];
#pragma unroll
                    for (int p = 0; p < 4; ++p) {
                        const int c = 32 + g * 4 + p;
                        uint4v b0 = RD(c & 3, 0), b1 = RD(c & 3, 1);
                        ISSUE(c + 2);
                        VMW2();
                        c2[2 * p]     = mfma16(a, b0, c2[2 * p]);
                        c2[2 * p + 1] = mfma16(a, b1, c2[2 * p + 1]);
                    }
                }
#pragma unroll
                for (int c = 0; c < 8; ++c)
#pragma unroll
                    for (int j = 0; j < 4; ++j)
                        h2[lg * 4 + j][hc0 + c * 16 + lr] = f2bf(ftanh(c2[c][j] + bias2[c]));
            }
            BAR();

            // ======== layer 3: k = h2 @ W3 + b3 — chunks 160..191 (wraps) ====
            {
                f32x4 c30 = z4, c31 = z4;
#pragma unroll 4
                for (int g = 0; g < 32; ++g) {
                    uint4v a = *(const uint4v*)&h2[lr][g * 32 + lg * 8];
                    const int c = 160 + g;
                    uint4v b0 = RD(c & 3, 0), b1 = RD(c & 3, 1);
                    int cc = (g < 30) ? (c + 2) : (g - 30);   // wrap into next stage
                    ISSUE(cc);
                    VMW2();
                    c30 = mfma16(a, b0, c30);
                    c31 = mfma16(a, b1, c31);
                }

                float accw = (stage == 0 || stage == 3) ? 1.0f : 2.0f;
                float cin  = (stage == 2) ? dt : 0.5f * dt;
                f32x4 c3p[2]; c3p[0] = c30; c3p[1] = c31;
#pragma unroll
                for (int t = 0; t < 2; ++t)
#pragma unroll
                    for (int j = 0; j < 4; ++j) {
                        float kv = c3p[t][j] + bias3[t];
                        acc[t][j] = (stage == 0) ? kv : acc[t][j] + accw * kv;
                        float ysv;
                        if (stage < 3) {
                            ysv = yreg[t][j] + cin * kv;
                        } else {
                            yreg[t][j] += dt * (1.0f / 6.0f) * acc[t][j];
                            ysv = yreg[t][j];
                            __builtin_nontemporal_store(
                                ysv, &out[((s0 + lg * 4 + j) * NT + step) * DIM + dc0 + t * 16 + lr]);
                        }
                        ys[lg * 4 + j][dc0 + t * 16 + lr] = f2bf(ysv);
                    }
            }
            BAR();
        }
    }
    // drain outstanding DMA before wave exit
    asm volatile("s_waitcnt vmcnt(0)" ::: "memory");
}

extern "C" void kernel_launch(void* const* d_in, const int* in_sizes, int n_in,
                              void* d_out, int out_size, void* d_ws, size_t ws_size,
                              hipStream_t stream) {
    const float* y0 = (const float*)d_in[0];
    const float* ts = (const float*)d_in[1];
    const float* W1 = (const float*)d_in[2];
    const float* b1 = (const float*)d_in[3];
    const float* W2 = (const float*)d_in[4];
    const float* b2 = (const float*)d_in[5];
    const float* W3 = (const float*)d_in[6];
    const float* b3 = (const float*)d_in[7];
    unsigned short* ws = (unsigned short*)d_ws;
    float* out = (float*)d_out;

    prep_kernel<<<3072, 64, 0, stream>>>(W1, W2, W3, ws);
    ode_main<<<NBLK, NTHR, 0, stream>>>(y0, ts, b1, b2, b3, ws, out);
}